// Round 6
// baseline (171.715 us; speedup 1.0000x reference)
//
#include <hip/hip_runtime.h>

#define BB 16
#define NN 1024
#define CC 64

typedef __attribute__((ext_vector_type(8))) short short8;
typedef __attribute__((ext_vector_type(4))) float f32x4;
typedef __attribute__((ext_vector_type(4))) int   i32x4;

typedef __attribute__((address_space(3))) void lds_void_t;
typedef const __attribute__((address_space(1))) void gbl_void_t;

__device__ __forceinline__ void load_lds16(const void* g, void* l) {
    __builtin_amdgcn_global_load_lds((gbl_void_t*)g, (lds_void_t*)l, 16, 0, 0);
}

__device__ __forceinline__ unsigned short bf16_rne(float f) {
    unsigned u = __float_as_uint(f);
    u += 0x7fffu + ((u >> 16) & 1u);
    return (unsigned short)(u >> 16);
}

// ---------------- Kernel 1: xw = x@W_rel -> bf16 swizzled (B-frag order);
//                  out = x@W_root + b_rel (fp32) ---------------- (unchanged)
extern "C" __global__ __launch_bounds__(256)
void precompute(const float* __restrict__ x, const float* __restrict__ W_rel,
                const float* __restrict__ W_root, const float* __restrict__ b_rel,
                unsigned short* __restrict__ xw_sw, float* __restrict__ out)
{
    __shared__ float wrel_s[64 * 64];
    __shared__ float wroot_s[64 * 64];
    __shared__ float x_s[16 * 68];

    const int t = threadIdx.x;
    #pragma unroll
    for (int k = 0; k < 4; ++k) {
        int i4 = t + 256 * k;
        ((float4*)wrel_s)[i4]  = ((const float4*)W_rel)[i4];
        ((float4*)wroot_s)[i4] = ((const float4*)W_root)[i4];
    }
    const int row0 = blockIdx.x * 16;
    {
        int r = t >> 4, c4 = t & 15;
        *(float4*)(x_s + r * 68 + c4 * 4) = ((const float4*)(x + (size_t)(row0 + r) * CC))[c4];
    }
    __syncthreads();

    const int c4 = t & 15;
    const int r  = t >> 4;
    float aw0 = 0.f, aw1 = 0.f, aw2 = 0.f, aw3 = 0.f;
    float ar0 = 0.f, ar1 = 0.f, ar2 = 0.f, ar3 = 0.f;
    const float* xrow = x_s + r * 68;
    #pragma unroll 8
    for (int k = 0; k < 64; ++k) {
        float xv = xrow[k];
        float4 wv = ((const float4*)(wrel_s  + k * 64))[c4];
        float4 rv = ((const float4*)(wroot_s + k * 64))[c4];
        aw0 += xv * wv.x; aw1 += xv * wv.y; aw2 += xv * wv.z; aw3 += xv * wv.w;
        ar0 += xv * rv.x; ar1 += xv * rv.y; ar2 += xv * rv.z; ar3 += xv * rv.w;
    }

    const int row_g = row0 + r;
    {
        const float4 bv = ((const float4*)b_rel)[c4];
        ((float4*)out)[(size_t)row_g * 16 + c4] =
            make_float4(ar0 + bv.x, ar1 + bv.y, ar2 + bv.z, ar3 + bv.w);
    }
    {
        const int b = row_g >> 10;
        const int k = row_g & 1023;
        const int kb = k >> 5;
        const int qk = (k >> 3) & 3;
        const int j  = k & 7;
        const int c  = 4 * c4;
        const int n0 = c >> 4;
        const int n  = c & 15;
        size_t off = ((size_t)b << 16) + (size_t)((kb * 4 + n0) << 9)
                   + (size_t)((n + (qk << 4)) << 3) + j;
        xw_sw[off]      = bf16_rne(aw0);
        xw_sw[off + 8]  = bf16_rne(aw1);
        xw_sw[off + 16] = bf16_rne(aw2);
        xw_sw[off + 24] = bf16_rne(aw3);
    }
}

// ---------------- Kernel 2: out += (adj .* w_edge[ea]) @ xw  (bf16 MFMA) ----
// grid = B * (N/32) * 2 = 1024 blocks x 256 threads.
// Block = (batch, 32-row m-tile, K-half of 512). K processed in 8 chunks of 64,
// DOUBLE-BUFFERED (24 KB x 2 = 48 KB LDS, 3 blocks/CU), with hand-written
// barriers: `s_waitcnt vmcnt(6); s_barrier` keeps the NEXT chunk's 6 DMA loads
// per wave in flight across the barrier (AITER-style), instead of the full
// vmcnt(0) drain __syncthreads() would emit. Buffer-reuse barrier is a
// drain-free `lgkmcnt(0); s_barrier`.
#define CHUNK_B 24576   // per-buffer: adj 8K | ea 8K | xw 8K

extern "C" __global__ __launch_bounds__(256, 3)
void gnn_mfma(const float* __restrict__ adj, const int* __restrict__ ea,
              const float* __restrict__ w_edge,
              const unsigned short* __restrict__ xw_sw,
              float* __restrict__ out)
{
    __shared__ __align__(16) char lds[2 * CHUNK_B];

    const int t    = threadIdx.x;
    const int w    = t >> 6;
    const int lane = t & 63;
    const int m    = lane & 15;
    const int q    = lane >> 4;
    const int wm   = w >> 1;
    const int wk   = w & 1;

    const int mtile = blockIdx.x & 31;
    const int kh    = (blockIdx.x >> 5) & 1;
    const int b     = blockIdx.x >> 6;
    const int row0  = mtile << 5;

    // cubic through (e, w_edge[e]) for e=0..3 — exact branchless gather
    const float w0 = w_edge[0], w1 = w_edge[1], w2 = w_edge[2], w3 = w_edge[3];
    const float d1 = w1 - w0;
    const float d2 = w2 - 2.f * w1 + w0;
    const float d3 = w3 - 3.f * w2 + 3.f * w1 - w0;
    const float c3 = d3 * (1.f / 6.f);
    const float c2 = 0.5f * d2 - 0.5f * d3;
    const float c1 = d1 - 0.5f * d2 + (1.f / 3.f) * d3;
    const float c0 = w0;

    const size_t bbase = ((size_t)b << 20);
    const unsigned short* xwb = xw_sw + ((size_t)b << 16);

    f32x4 acc0 = {0.f, 0.f, 0.f, 0.f};
    f32x4 acc1 = acc0, acc2 = acc0, acc3 = acc0;

    // ---- staging for chunk c into buffer c&1: 6 DMA per wave ----
    #define STAGE(c)                                                            \
    {                                                                           \
        const int buf = ((c) & 1) * CHUNK_B;                                    \
        const int kc  = (kh << 9) + ((c) << 6);                                 \
        _Pragma("unroll")                                                       \
        for (int r = 0; r < 2; ++r) {                                           \
            int f  = w + (r << 2);            /* 0..7 */                        \
            int mh = f >> 2, kb = (f >> 1) & 1, h = f & 1;                      \
            int row = row0 + (mh << 4) + m;                                     \
            int k   = kc + (kb << 5) + (q << 3) + (h << 2);                     \
            size_t goff = bbase + ((size_t)row << 10) + k;                      \
            int doff = buf + (((mh << 1) + kb) << 11) + (h << 10);              \
            load_lds16(adj + goff, lds + doff);                                 \
            load_lds16(ea  + goff, lds + 8192 + doff);                          \
        }                                                                       \
        _Pragma("unroll")                                                       \
        for (int r = 0; r < 2; ++r) {                                           \
            int f  = w + (r << 2);                                              \
            int kb = f >> 2, n0 = f & 3;                                        \
            int kbg = (kh << 4) + ((c) << 1) + kb;                              \
            load_lds16(xwb + (((kbg << 2) + n0) << 9) + (lane << 3),            \
                       lds + buf + 16384 + (f << 10));                          \
        }                                                                       \
    }

    STAGE(0);

    #pragma unroll
    for (int c = 0; c < 8; ++c) {
        if (c < 7) STAGE(c + 1);

        // wait for OLDER chunk's DMA only; newer 6 stay in flight
        if (c < 7) asm volatile("s_waitcnt vmcnt(6)\n\ts_barrier" ::: "memory");
        else       asm volatile("s_waitcnt vmcnt(0)\n\ts_barrier" ::: "memory");

        // ---- compute chunk c: one 16x16x32 k-step per wave ----
        {
            const int buf  = (c & 1) * CHUNK_B;
            const int frag = (wm << 1) + wk;
            const char* ab = lds + buf + (frag << 11) + (lane << 4);
            f32x4 alo = *(const f32x4*)(ab);
            f32x4 ahi = *(const f32x4*)(ab + 1024);
            i32x4 elo = *(const i32x4*)(ab + 8192);
            i32x4 ehi = *(const i32x4*)(ab + 8192 + 1024);

            #define WSEL(ev) __builtin_fmaf(__builtin_fmaf(__builtin_fmaf(c3, (float)(ev), c2), (float)(ev), c1), (float)(ev), c0)
            float p0 = alo[0] * WSEL(elo[0]);
            float p1 = alo[1] * WSEL(elo[1]);
            float p2 = alo[2] * WSEL(elo[2]);
            float p3 = alo[3] * WSEL(elo[3]);
            float p4 = ahi[0] * WSEL(ehi[0]);
            float p5 = ahi[1] * WSEL(ehi[1]);
            float p6 = ahi[2] * WSEL(ehi[2]);
            float p7 = ahi[3] * WSEL(ehi[3]);
            #undef WSEL

            union { int i[4]; short8 s8; } af;
            af.i[0] = __builtin_amdgcn_perm(__float_as_uint(p1), __float_as_uint(p0), 0x07060302u);
            af.i[1] = __builtin_amdgcn_perm(__float_as_uint(p3), __float_as_uint(p2), 0x07060302u);
            af.i[2] = __builtin_amdgcn_perm(__float_as_uint(p5), __float_as_uint(p4), 0x07060302u);
            af.i[3] = __builtin_amdgcn_perm(__float_as_uint(p7), __float_as_uint(p6), 0x07060302u);

            const char* xbase = lds + buf + 16384 + ((wk << 2) << 10) + (lane << 4);
            short8 bf0 = *(const short8*)(xbase);
            short8 bf1 = *(const short8*)(xbase + 1024);
            short8 bf2 = *(const short8*)(xbase + 2048);
            short8 bf3 = *(const short8*)(xbase + 3072);

            acc0 = __builtin_amdgcn_mfma_f32_16x16x32_bf16(af.s8, bf0, acc0, 0, 0, 0);
            acc1 = __builtin_amdgcn_mfma_f32_16x16x32_bf16(af.s8, bf1, acc1, 0, 0, 0);
            acc2 = __builtin_amdgcn_mfma_f32_16x16x32_bf16(af.s8, bf2, acc2, 0, 0, 0);
            acc3 = __builtin_amdgcn_mfma_f32_16x16x32_bf16(af.s8, bf3, acc3, 0, 0, 0);
        }

        // buffer-reuse barrier (no vmem drain): needed while staging continues
        if (c < 6) asm volatile("s_waitcnt lgkmcnt(0)\n\ts_barrier" ::: "memory");
    }
    #undef STAGE

    // ---- combine wk pairs via LDS (stride-68, conflict-free), atomicAdd out ----
    __syncthreads();
    float* scratch = (float*)lds;
    if (wk == 1) {
        float* buf = scratch + wm * 1088;
        #pragma unroll
        for (int rg = 0; rg < 4; ++rg) {
            int rbase = (q * 4 + rg) * 68 + m;
            buf[rbase]      = acc0[rg];
            buf[rbase + 16] = acc1[rg];
            buf[rbase + 32] = acc2[rg];
            buf[rbase + 48] = acc3[rg];
        }
    }
    __syncthreads();
    if (wk == 0) {
        const float* buf = scratch + wm * 1088;
        float* obase = out + (((size_t)b << 10) + row0 + (wm << 4)) * 64;
        #pragma unroll
        for (int rg = 0; rg < 4; ++rg) {
            int rpad = (q * 4 + rg) * 68 + m;
            int rout = (q * 4 + rg) * 64 + m;
            #pragma unroll
            for (int n0 = 0; n0 < 4; ++n0) {
                float v = (n0 == 0 ? acc0[rg] : n0 == 1 ? acc1[rg] : n0 == 2 ? acc2[rg] : acc3[rg]);
                v += buf[rpad + n0 * 16];
                atomicAdd(obase + rout + n0 * 16, v);
            }
        }
    }
}

extern "C" void kernel_launch(void* const* d_in, const int* in_sizes, int n_in,
                              void* d_out, int out_size, void* d_ws, size_t ws_size,
                              hipStream_t stream) {
    const float* x      = (const float*)d_in[0];
    const float* adj    = (const float*)d_in[1];
    const int*   ea     = (const int*)  d_in[2];
    const float* W_rel  = (const float*)d_in[3];
    const float* b_rel  = (const float*)d_in[4];
    const float* W_root = (const float*)d_in[5];
    const float* w_edge = (const float*)d_in[6];
    float* out = (float*)d_out;

    unsigned short* xw_sw = (unsigned short*)d_ws;   // B*N*C bf16 = 2 MiB

    precompute<<<BB * NN / 16, 256, 0, stream>>>(x, W_rel, W_root, b_rel, xw_sw, out);
    gnn_mfma<<<BB * (NN / 32) * 2, 256, 0, stream>>>(adj, ea, w_edge, xw_sw, out);
}